// Round 19
// baseline (223.647 us; speedup 1.0000x reference)
//
#include <hip/hip_runtime.h>

typedef unsigned short u16;
typedef __attribute__((ext_vector_type(8))) short s8v;   // 8 x bf16 (4 VGPR)
typedef __attribute__((ext_vector_type(4))) float f4v;   // MFMA accum

#define MFMA16(a, b, c) __builtin_amdgcn_mfma_f32_16x16x32_bf16(a, b, c, 0, 0, 0)

#define TSEQ 2048
#define NTOK 4096          // B*T
#define HEADS 32           // H*B
#define HB_ELEMS 131072    // T*dh elems per head block

__device__ __forceinline__ unsigned cvt_pk(float lo, float hi) {
  unsigned r;
  asm("v_cvt_pk_bf16_f32 %0, %1, %2" : "=v"(r) : "v"(lo), "v"(hi));
  return r;
}

__device__ __forceinline__ void gl_lds16(const u16* g, u16* l) {
  __builtin_amdgcn_global_load_lds(
      (const __attribute__((address_space(1))) void*)g,
      (__attribute__((address_space(3))) void*)l, 16, 0, 0);
}

// ---------------- fused fp32 -> bf16 convert (all 6 tensors, one launch) -----
__global__ void cvt_all(const float* __restrict__ q, const float* __restrict__ k,
                        const float* __restrict__ v, const float* __restrict__ wq,
                        const float* __restrict__ wk, const float* __restrict__ wv,
                        u16* __restrict__ dst) {
  int i = (blockIdx.x * blockDim.x + threadIdx.x) * 4;
  const float* src; int off;
  if (i < 12582912) {
    int s = i >> 22; src = (s == 0) ? q : ((s == 1) ? k : v); off = i & 4194303;
  } else {
    int j = i - 12582912;
    int s = j >> 20; src = (s == 0) ? wq : ((s == 1) ? wk : wv); off = j & 1048575;
  }
  float4 val = *(const float4*)(src + off);
  uint2 o;
  o.x = cvt_pk(val.x, val.y);
  o.y = cvt_pk(val.z, val.w);
  *(uint2*)(dst + i) = o;
}

// ---------------- projection GEMM: C = A(4096x1024) * W(1024x1024)^T + bias ----
__launch_bounds__(256, 3)
__global__ void proj_gemm(const u16* __restrict__ Aall, const u16* __restrict__ Wall,
                          const float* __restrict__ bqp, const float* __restrict__ bkp,
                          const float* __restrict__ bvp, u16* __restrict__ Call) {
  const int z = blockIdx.z;
  const u16* A = Aall + (size_t)z * 4194304;
  const u16* W = Wall + (size_t)z * 1048576;
  u16* C = Call + (size_t)z * 4194304;
  const float* bias = (z == 0) ? bqp : ((z == 1) ? bkp : bvp);

  __shared__ __align__(16) u16 SH[17408];   // As[0..8K) Bs[8K..16K); T[128][136]
  u16* As = SH;
  u16* Bs = SH + 8192;

  const int tid = threadIdx.x;
  const int w = tid >> 6, lane = tid & 63, g = lane >> 4, l = lane & 15;
  const int wr = w >> 1, wc = w & 1;
  const int tr = blockIdx.y * 128, tc = blockIdx.x * 128;

  const int srow = tid >> 3;        // 0..31  (staging row within 32-row chunk)
  const int scol = (tid & 7) * 8;   // elem col within 64

  f4v acc[4][4] = {};

  for (int kt = 0; kt < 1024; kt += 64) {
#pragma unroll
    for (int c4 = 0; c4 < 4; ++c4) {
      gl_lds16(A + (size_t)(tr + c4 * 32 + srow) * 1024 + kt + scol,
               As + c4 * 2048 + tid * 8);
      gl_lds16(W + (size_t)(tc + c4 * 32 + srow) * 1024 + kt + scol,
               Bs + c4 * 2048 + tid * 8);
    }
    __syncthreads();
#pragma unroll
    for (int ks = 0; ks < 2; ++ks) {
      s8v a[4], bb[4];
#pragma unroll
      for (int m = 0; m < 4; ++m)
        a[m] = *(const s8v*)(As + (wr * 64 + m * 16 + l) * 64 + ks * 32 + g * 8);
#pragma unroll
      for (int n = 0; n < 4; ++n)
        bb[n] = *(const s8v*)(Bs + (wc * 64 + n * 16 + l) * 64 + ks * 32 + g * 8);
#pragma unroll
      for (int m = 0; m < 4; ++m)
#pragma unroll
        for (int n = 0; n < 4; ++n)
          acc[m][n] = MFMA16(a[m], bb[n], acc[m][n]);
    }
    __syncthreads();
  }
  // ---- epilogue: bias + bf16 pack into LDS tile T[t 128][d 136], then
  // coalesced 16B global stores.
  u16* T = SH;
#pragma unroll
  for (int m = 0; m < 4; ++m)
#pragma unroll
    for (int n = 0; n < 4; ++n) {
      int d = wc * 64 + n * 16 + l;
      float bv = bias[tc + d];
      unsigned c01 = cvt_pk(acc[m][n][0] + bv, acc[m][n][1] + bv);
      unsigned c23 = cvt_pk(acc[m][n][2] + bv, acc[m][n][3] + bv);
      int t0 = wr * 64 + m * 16 + g * 4;
      T[(t0 + 0) * 136 + d] = (u16)c01;
      T[(t0 + 1) * 136 + d] = (u16)(c01 >> 16);
      T[(t0 + 2) * 136 + d] = (u16)c23;
      T[(t0 + 3) * 136 + d] = (u16)(c23 >> 16);
    }
  __syncthreads();
#pragma unroll
  for (int it = 0; it < 8; ++it) {
    int t = it * 16 + (tid >> 4);
    int c8 = (tid & 15) * 8;
    *(s8v*)(C + (size_t)(tr + t) * 1024 + tc + c8) = *(const s8v*)&T[t * 136 + c8];
  }
}

// ---------------- per-head V transpose: vT[hb][d][t] = vp[hb][t][d] ----------
__global__ void vtrans(const u16* __restrict__ vp, u16* __restrict__ vT) {
  const int hb = blockIdx.y;
  const int t0 = blockIdx.x * 64;
  const int tid = threadIdx.x;
  __shared__ u16 tl[64][65];
  const u16* vph = vp + (size_t)hb * HB_ELEMS;
  u16* vth = vT + (size_t)hb * HB_ELEMS;
#pragma unroll
  for (int it = 0; it < 4; ++it) {
    int i = (tid + it * 256) * 4;
    int r = i >> 6, c = i & 63;
    *(ushort4*)&tl[r][c] = *(const ushort4*)(vph + (size_t)(t0 + r) * 64 + c);
  }
  __syncthreads();
#pragma unroll
  for (int it = 0; it < 4; ++it) {
    int i = (tid + it * 256) * 4;
    int d = i >> 6, j = i & 63;
    ushort4 o;
    o.x = tl[j + 0][d]; o.y = tl[j + 1][d]; o.z = tl[j + 2][d]; o.w = tl[j + 3][d];
    *(ushort4*)(vth + (size_t)d * TSEQ + t0 + j) = o;
  }
}

// ---------------- fused attention: 128-row q-tiles, 8 waves -----------------
// grid: 512 blocks (16 qtiles x 32 heads, XCD-swizzled); 8 waves x 16 q-rows.
// R16 structure + DEFENSIVE barrier C between Pf writes and PV reads: the
// P handoff is cross-lane within a wave, and relying on compiler-inserted
// lgkmcnt ordering proved codegen-fragile (R15/R18 failures). Barrier makes
// the ordering architectural.
__launch_bounds__(512, 2)
__global__ void attn_fused(const u16* __restrict__ qp, const u16* __restrict__ kp,
                           const u16* __restrict__ vT, float* __restrict__ attn,
                           float* __restrict__ ctx) {
  // XCD-bijective swizzle: all 16 q-tiles of a head share (hw & 7) -> same XCD
  const int hw = blockIdx.x + (blockIdx.y << 4);
  const int hb = (hw & 7) + ((hw >> 7) << 3);
  const int qt = (hw >> 3) & 15;

  const int tid = threadIdx.x;                    // 0..511
  const int w = tid >> 6, lane = tid & 63, g = lane >> 4, l = lane & 15;
  const int lx = l & 7;

  const u16* qh = qp + (size_t)hb * HB_ELEMS;
  const u16* kh = kp + (size_t)hb * HB_ELEMS;
  const u16* vh = vT + (size_t)hb * HB_ELEMS;

  // pass1: K[256][64] (32KB). pass2: Kl 8KB | Vl 8KB | Pf[128][72] f32 36.9KB.
  __shared__ __align__(16) u16 SH[26624];         // 52 KB

  const int row0 = qt * 128 + w * 16;             // wave's 16 q-rows
  const float scale = 0.125f;                     // dh^-0.5

  // staging geometry: thread t covers row (t>>3), 16B chunk t&7
  const int srow = tid >> 3;                      // 0..63
  const int swc = ((tid & 7) ^ (srow & 7)) * 8;   // swizzled source col (elems)

  // Q as B-operand fragment: lane (g,l) holds Q[row0+l][ks*32+g*8 .. +8)
  s8v qf0 = *(const s8v*)(qh + (size_t)(row0 + l) * 64 + g * 8);
  s8v qf1 = *(const s8v*)(qh + (size_t)(row0 + l) * 64 + 32 + g * 8);

  // ---- pass 1: row sums of exp(score); swapped mfma(K,Q) => C col = q-row l
  float sum = 0.0f;
  for (int kt4 = 0; kt4 < 8; ++kt4) {
    const int c0 = kt4 * 256;
#pragma unroll
    for (int c4 = 0; c4 < 4; ++c4)
      gl_lds16(kh + (size_t)(c0 + c4 * 64 + srow) * 64 + swc,
               SH + c4 * 4096 + tid * 8);
    __syncthreads();
#pragma unroll
    for (int q4 = 0; q4 < 4; ++q4) {
#pragma unroll
      for (int n = 0; n < 4; ++n) {
        const u16* kr = SH + q4 * 4096 + (n * 16 + l) * 64;
        s8v b0 = *(const s8v*)(kr + (g ^ lx) * 8);
        s8v b1 = *(const s8v*)(kr + ((4 + g) ^ lx) * 8);
        f4v s = {};
        s = MFMA16(b0, qf0, s);
        s = MFMA16(b1, qf1, s);
        sum += __expf(s[0] * scale) + __expf(s[1] * scale)
             + __expf(s[2] * scale) + __expf(s[3] * scale);
      }
    }
    __syncthreads();
  }
  // reduce across the 4 g-groups holding the same q-row l
  sum += __shfl_xor(sum, 16);
  sum += __shfl_xor(sum, 32);
  const float inv = 1.0f / sum;

  // ---- pass 2: recompute, P -> fp32 LDS, PV, post-barrier coalesced store --
  u16* Kl = SH;                       // [64][64] bf16 swizzled (8 KB)
  u16* Vl = SH + 4096;                // [64][64] bf16 swizzled (8 KB)
  float* Pf = (float*)(SH + 8192);    // [128][72] f32 P tile (36.9 KB)

  f4v cacc[4] = {};
  float* attn_h = attn + (size_t)hb * TSEQ * TSEQ;
  const int kt0 = (qt * 2 + ((hw >> 7) << 3)) & 31;  // column-window rotation
  const int prow = w * 16 + l;                    // this lane's P row
  const int st_r = tid >> 4;                      // store-phase row 0..31
  const int st_c = (tid & 15) * 4;                // store-phase float col
  for (int i = 0; i < 32; ++i) {
    const int kt = (i + kt0) & 31;
    const int col0 = kt * 64;
    gl_lds16(kh + (size_t)(col0 + srow) * 64 + swc, Kl + tid * 8);
    gl_lds16(vh + (size_t)srow * TSEQ + col0 + swc, Vl + tid * 8);
    __syncthreads();   // A: stage complete; prev store-phase Pf reads done
#pragma unroll
    for (int n = 0; n < 4; ++n) {
      const u16* kr = Kl + (n * 16 + l) * 64;
      s8v b0 = *(const s8v*)(kr + (g ^ lx) * 8);
      s8v b1 = *(const s8v*)(kr + ((4 + g) ^ lx) * 8);
      f4v s = {};
      s = MFMA16(b0, qf0, s);
      s = MFMA16(b1, qf1, s);
      f4v p;
#pragma unroll
      for (int r = 0; r < 4; ++r) p[r] = __expf(s[r] * scale) * inv;
      // P[q-row l][keys n*16+g*4 .. +4) for this wave
      *(f4v*)&Pf[prow * 72 + n * 16 + g * 4] = p;
    }
    __syncthreads();   // C: ALL Pf writes architecturally visible before PV
    // PV for this 64-key tile: read P rows, pack bf16 on the fly
#pragma unroll
    for (int ks = 0; ks < 2; ++ks) {
      const float* pr = &Pf[prow * 72 + ks * 32 + g * 8];
      f4v r0 = *(const f4v*)pr;
      f4v r1 = *(const f4v*)(pr + 4);
      union { unsigned u[4]; s8v s; } pc;
      pc.u[0] = cvt_pk(r0[0], r0[1]);
      pc.u[1] = cvt_pk(r0[2], r0[3]);
      pc.u[2] = cvt_pk(r1[0], r1[1]);
      pc.u[3] = cvt_pk(r1[2], r1[3]);
      s8v pa = pc.s;
#pragma unroll
      for (int n4 = 0; n4 < 4; ++n4) {
        const u16* vr = Vl + (n4 * 16 + l) * 64;
        s8v bvv = *(const s8v*)(vr + ((ks * 4 + g) ^ lx) * 8);
        cacc[n4] = MFMA16(pa, bvv, cacc[n4]);
      }
    }
    __syncthreads();   // B: PV's Pf reads done; K/V reads done
    // store phase: 4 rounds x (32 rows x 256B contiguous per row)
#pragma unroll
    for (int r4 = 0; r4 < 4; ++r4) {
      const int rho = r4 * 32 + st_r;
      f4v pv_ = *(const f4v*)&Pf[rho * 72 + st_c];
      *(f4v*)(attn_h + (size_t)(qt * 128 + rho) * TSEQ + col0 + st_c) = pv_;
    }
  }
  // write ctx (flat layout == (B,T,D) row-major); C row = q-row = g*4+r
#pragma unroll
  for (int n4 = 0; n4 < 4; ++n4)
#pragma unroll
    for (int r = 0; r < 4; ++r)
      ctx[(size_t)hb * HB_ELEMS + (size_t)(row0 + g * 4 + r) * 64 + n4 * 16 + l] =
          cacc[n4][r];
}

// ---------------- residual + LayerNorm ----------------
__global__ void ln_kernel(const float* __restrict__ q, const float* __restrict__ ctx,
                          const float* __restrict__ gam, const float* __restrict__ bet,
                          float* __restrict__ out) {
  const int row = blockIdx.x;
  const int tid = threadIdx.x;
  const float* qr = q + (size_t)row * 1024;
  const float* cr = ctx + (size_t)row * 1024;
  float4 xq = *(const float4*)(qr + tid * 4);
  float4 xc = *(const float4*)(cr + tid * 4);
  float x0 = xq.x + xc.x, x1 = xq.y + xc.y, x2 = xq.z + xc.z, x3 = xq.w + xc.w;
  float s1 = x0 + x1 + x2 + x3;
  float s2 = x0 * x0 + x1 * x1 + x2 * x2 + x3 * x3;
#pragma unroll
  for (int off = 1; off < 64; off <<= 1) {
    s1 += __shfl_xor(s1, off);
    s2 += __shfl_xor(s2, off);
  }
  __shared__ float ra[4], rb[4];
  int w = tid >> 6, lane = tid & 63;
  if (lane == 0) { ra[w] = s1; rb[w] = s2; }
  __syncthreads();
  s1 = ra[0] + ra[1] + ra[2] + ra[3];
  s2 = rb[0] + rb[1] + rb[2] + rb[3];
  float mu = s1 * (1.0f / 1024.0f);
  float var = s2 * (1.0f / 1024.0f) - mu * mu;
  float rstd = rsqrtf(var + 1e-5f);
  float4 gv = *(const float4*)(gam + tid * 4);
  float4 bv = *(const float4*)(bet + tid * 4);
  float4 o;
  o.x = (x0 - mu) * rstd * gv.x + bv.x;
  o.y = (x1 - mu) * rstd * gv.y + bv.y;
  o.z = (x2 - mu) * rstd * gv.z + bv.z;
  o.w = (x3 - mu) * rstd * gv.w + bv.w;
  *(float4*)(out + (size_t)row * 1024 + tid * 4) = o;
}

extern "C" void kernel_launch(void* const* d_in, const int* in_sizes, int n_in,
                              void* d_out, int out_size, void* d_ws, size_t ws_size,
                              hipStream_t stream) {
  const float* q    = (const float*)d_in[0];
  const float* k    = (const float*)d_in[1];
  const float* v    = (const float*)d_in[2];
  const float* wq   = (const float*)d_in[3];
  const float* bq   = (const float*)d_in[4];
  const float* wk   = (const float*)d_in[5];
  const float* bk   = (const float*)d_in[6];
  const float* wv   = (const float*)d_in[7];
  const float* bv   = (const float*)d_in[8];
  const float* ln_g = (const float*)d_in[9];
  const float* ln_b = (const float*)d_in[10];

  char* ws = (char*)d_ws;
  u16* qbf  = (u16*)(ws);              // 3 x 8 MiB   bf16 inputs (q,k,v)
  u16* wbf  = (u16*)(ws + 25165824);   // 3 x 2 MiB   bf16 weights (contig w/ qbf)
  u16* qp   = (u16*)(ws + 31457280);   // 3 x 8 MiB   bf16 projections (qp,kp,vp)
  u16* vT   = (u16*)(ws + 56623104);   // 8 MiB       per-head transposed V
  float* ctx = (float*)(ws + 65011712); // 16 MiB     fp32 context

  float* out  = (float*)d_out;
  float* attn = out + 4194304;

  cvt_all<<<15360, 256, 0, stream>>>(q, k, v, wq, wk, wv, qbf);

  proj_gemm<<<dim3(8, 32, 3), 256, 0, stream>>>(qbf, wbf, bq, bk, bv, qp);

  vtrans<<<dim3(32, 32), 256, 0, stream>>>(qp + 8388608, vT);

  attn_fused<<<dim3(16, 32), 512, 0, stream>>>(qp, qp + 4194304, vT, attn, ctx);

  ln_kernel<<<4096, 256, 0, stream>>>(q, ctx, ln_g, ln_b, out);
}

// Round 20
// 222.400 us; speedup vs baseline: 1.0056x; 1.0056x over previous
//
#include <hip/hip_runtime.h>

typedef unsigned short u16;
typedef __attribute__((ext_vector_type(8))) short s8v;   // 8 x bf16 (4 VGPR)
typedef __attribute__((ext_vector_type(4))) float f4v;   // MFMA accum

#define MFMA16(a, b, c) __builtin_amdgcn_mfma_f32_16x16x32_bf16(a, b, c, 0, 0, 0)

#define TSEQ 2048
#define NTOK 4096          // B*T
#define HEADS 32           // H*B
#define HB_ELEMS 131072    // T*dh elems per head block

__device__ __forceinline__ unsigned cvt_pk(float lo, float hi) {
  unsigned r;
  asm("v_cvt_pk_bf16_f32 %0, %1, %2" : "=v"(r) : "v"(lo), "v"(hi));
  return r;
}

__device__ __forceinline__ void gl_lds16(const u16* g, u16* l) {
  __builtin_amdgcn_global_load_lds(
      (const __attribute__((address_space(1))) void*)g,
      (__attribute__((address_space(3))) void*)l, 16, 0, 0);
}

// ---------------- fused fp32 -> bf16 convert (all 6 tensors, one launch) -----
__global__ void cvt_all(const float* __restrict__ q, const float* __restrict__ k,
                        const float* __restrict__ v, const float* __restrict__ wq,
                        const float* __restrict__ wk, const float* __restrict__ wv,
                        u16* __restrict__ dst) {
  int i = (blockIdx.x * blockDim.x + threadIdx.x) * 4;
  const float* src; int off;
  if (i < 12582912) {
    int s = i >> 22; src = (s == 0) ? q : ((s == 1) ? k : v); off = i & 4194303;
  } else {
    int j = i - 12582912;
    int s = j >> 20; src = (s == 0) ? wq : ((s == 1) ? wk : wv); off = j & 1048575;
  }
  float4 val = *(const float4*)(src + off);
  uint2 o;
  o.x = cvt_pk(val.x, val.y);
  o.y = cvt_pk(val.z, val.w);
  *(uint2*)(dst + i) = o;
}

// ---------------- projection GEMM: C = A(4096x1024) * W(1024x1024)^T + bias ----
__launch_bounds__(256, 3)
__global__ void proj_gemm(const u16* __restrict__ Aall, const u16* __restrict__ Wall,
                          const float* __restrict__ bqp, const float* __restrict__ bkp,
                          const float* __restrict__ bvp, u16* __restrict__ Call) {
  const int z = blockIdx.z;
  const u16* A = Aall + (size_t)z * 4194304;
  const u16* W = Wall + (size_t)z * 1048576;
  u16* C = Call + (size_t)z * 4194304;
  const float* bias = (z == 0) ? bqp : ((z == 1) ? bkp : bvp);

  __shared__ __align__(16) u16 SH[17408];   // As[0..8K) Bs[8K..16K); T[128][136]
  u16* As = SH;
  u16* Bs = SH + 8192;

  const int tid = threadIdx.x;
  const int w = tid >> 6, lane = tid & 63, g = lane >> 4, l = lane & 15;
  const int wr = w >> 1, wc = w & 1;
  const int tr = blockIdx.y * 128, tc = blockIdx.x * 128;

  const int srow = tid >> 3;        // 0..31  (staging row within 32-row chunk)
  const int scol = (tid & 7) * 8;   // elem col within 64

  f4v acc[4][4] = {};

  for (int kt = 0; kt < 1024; kt += 64) {
#pragma unroll
    for (int c4 = 0; c4 < 4; ++c4) {
      gl_lds16(A + (size_t)(tr + c4 * 32 + srow) * 1024 + kt + scol,
               As + c4 * 2048 + tid * 8);
      gl_lds16(W + (size_t)(tc + c4 * 32 + srow) * 1024 + kt + scol,
               Bs + c4 * 2048 + tid * 8);
    }
    __syncthreads();
#pragma unroll
    for (int ks = 0; ks < 2; ++ks) {
      s8v a[4], bb[4];
#pragma unroll
      for (int m = 0; m < 4; ++m)
        a[m] = *(const s8v*)(As + (wr * 64 + m * 16 + l) * 64 + ks * 32 + g * 8);
#pragma unroll
      for (int n = 0; n < 4; ++n)
        bb[n] = *(const s8v*)(Bs + (wc * 64 + n * 16 + l) * 64 + ks * 32 + g * 8);
#pragma unroll
      for (int m = 0; m < 4; ++m)
#pragma unroll
        for (int n = 0; n < 4; ++n)
          acc[m][n] = MFMA16(a[m], bb[n], acc[m][n]);
    }
    __syncthreads();
  }
  // ---- epilogue: bias + bf16 pack into LDS tile T[t 128][d 136], then
  // coalesced 16B global stores.
  u16* T = SH;
#pragma unroll
  for (int m = 0; m < 4; ++m)
#pragma unroll
    for (int n = 0; n < 4; ++n) {
      int d = wc * 64 + n * 16 + l;
      float bv = bias[tc + d];
      unsigned c01 = cvt_pk(acc[m][n][0] + bv, acc[m][n][1] + bv);
      unsigned c23 = cvt_pk(acc[m][n][2] + bv, acc[m][n][3] + bv);
      int t0 = wr * 64 + m * 16 + g * 4;
      T[(t0 + 0) * 136 + d] = (u16)c01;
      T[(t0 + 1) * 136 + d] = (u16)(c01 >> 16);
      T[(t0 + 2) * 136 + d] = (u16)c23;
      T[(t0 + 3) * 136 + d] = (u16)(c23 >> 16);
    }
  __syncthreads();
#pragma unroll
  for (int it = 0; it < 8; ++it) {
    int t = it * 16 + (tid >> 4);
    int c8 = (tid & 15) * 8;
    *(s8v*)(C + (size_t)(tr + t) * 1024 + tc + c8) = *(const s8v*)&T[t * 136 + c8];
  }
}

// ---------------- per-head V transpose: vT[hb][d][t] = vp[hb][t][d] ----------
__global__ void vtrans(const u16* __restrict__ vp, u16* __restrict__ vT) {
  const int hb = blockIdx.y;
  const int t0 = blockIdx.x * 64;
  const int tid = threadIdx.x;
  __shared__ u16 tl[64][65];
  const u16* vph = vp + (size_t)hb * HB_ELEMS;
  u16* vth = vT + (size_t)hb * HB_ELEMS;
#pragma unroll
  for (int it = 0; it < 4; ++it) {
    int i = (tid + it * 256) * 4;
    int r = i >> 6, c = i & 63;
    *(ushort4*)&tl[r][c] = *(const ushort4*)(vph + (size_t)(t0 + r) * 64 + c);
  }
  __syncthreads();
#pragma unroll
  for (int it = 0; it < 4; ++it) {
    int i = (tid + it * 256) * 4;
    int d = i >> 6, j = i & 63;
    ushort4 o;
    o.x = tl[j + 0][d]; o.y = tl[j + 1][d]; o.z = tl[j + 2][d]; o.w = tl[j + 3][d];
    *(ushort4*)(vth + (size_t)d * TSEQ + t0 + j) = o;
  }
}

// ---------------- fused attention: 128-row q-tiles, 8 waves -----------------
// grid: 512 blocks (16 qtiles x 32 heads, XCD-swizzled); 8 waves x 16 q-rows.
// vs R19: (1) Pf stride 72 -> 76 floats: PV pr-read start-banks become
// uniform mod 32 (12l+8g covers all 8 quad-starts vs 8(l+g) covering 4) —
// removes the one 2x bank-conflicted access in the kernel. (2) barrier C ->
// wave-local lgkmcnt(0)+sched_barrier fence: Pf rows in the write/PV phase
// are wave-private, so a wave-level drain is architecturally sufficient.
__launch_bounds__(512, 2)
__global__ void attn_fused(const u16* __restrict__ qp, const u16* __restrict__ kp,
                           const u16* __restrict__ vT, float* __restrict__ attn,
                           float* __restrict__ ctx) {
  // XCD-bijective swizzle: all 16 q-tiles of a head share (hw & 7) -> same XCD
  const int hw = blockIdx.x + (blockIdx.y << 4);
  const int hb = (hw & 7) + ((hw >> 7) << 3);
  const int qt = (hw >> 3) & 15;

  const int tid = threadIdx.x;                    // 0..511
  const int w = tid >> 6, lane = tid & 63, g = lane >> 4, l = lane & 15;
  const int lx = l & 7;

  const u16* qh = qp + (size_t)hb * HB_ELEMS;
  const u16* kh = kp + (size_t)hb * HB_ELEMS;
  const u16* vh = vT + (size_t)hb * HB_ELEMS;

  // pass1: K[256][64] (32KB). pass2: Kl 8KB | Vl 8KB | Pf[128][76] f32 38.9KB.
  __shared__ __align__(16) u16 SH[27648];         // 54 KB

  const int row0 = qt * 128 + w * 16;             // wave's 16 q-rows
  const float scale = 0.125f;                     // dh^-0.5

  // staging geometry: thread t covers row (t>>3), 16B chunk t&7
  const int srow = tid >> 3;                      // 0..63
  const int swc = ((tid & 7) ^ (srow & 7)) * 8;   // swizzled source col (elems)

  // Q as B-operand fragment: lane (g,l) holds Q[row0+l][ks*32+g*8 .. +8)
  s8v qf0 = *(const s8v*)(qh + (size_t)(row0 + l) * 64 + g * 8);
  s8v qf1 = *(const s8v*)(qh + (size_t)(row0 + l) * 64 + 32 + g * 8);

  // ---- pass 1: row sums of exp(score); swapped mfma(K,Q) => C col = q-row l
  float sum = 0.0f;
  for (int kt4 = 0; kt4 < 8; ++kt4) {
    const int c0 = kt4 * 256;
#pragma unroll
    for (int c4 = 0; c4 < 4; ++c4)
      gl_lds16(kh + (size_t)(c0 + c4 * 64 + srow) * 64 + swc,
               SH + c4 * 4096 + tid * 8);
    __syncthreads();
#pragma unroll
    for (int q4 = 0; q4 < 4; ++q4) {
#pragma unroll
      for (int n = 0; n < 4; ++n) {
        const u16* kr = SH + q4 * 4096 + (n * 16 + l) * 64;
        s8v b0 = *(const s8v*)(kr + (g ^ lx) * 8);
        s8v b1 = *(const s8v*)(kr + ((4 + g) ^ lx) * 8);
        f4v s = {};
        s = MFMA16(b0, qf0, s);
        s = MFMA16(b1, qf1, s);
        sum += __expf(s[0] * scale) + __expf(s[1] * scale)
             + __expf(s[2] * scale) + __expf(s[3] * scale);
      }
    }
    __syncthreads();
  }
  // reduce across the 4 g-groups holding the same q-row l
  sum += __shfl_xor(sum, 16);
  sum += __shfl_xor(sum, 32);
  const float inv = 1.0f / sum;

  // ---- pass 2: recompute, P -> fp32 LDS, PV, post-barrier coalesced store --
  u16* Kl = SH;                       // [64][64] bf16 swizzled (8 KB)
  u16* Vl = SH + 4096;                // [64][64] bf16 swizzled (8 KB)
  float* Pf = (float*)(SH + 8192);    // [128][76] f32 P tile (38.9 KB)

  f4v cacc[4] = {};
  float* attn_h = attn + (size_t)hb * TSEQ * TSEQ;
  const int kt0 = (qt * 2 + ((hw >> 7) << 3)) & 31;  // column-window rotation
  const int prow = w * 16 + l;                    // this lane's P row
  const int st_r = tid >> 4;                      // store-phase row 0..31
  const int st_c = (tid & 15) * 4;                // store-phase float col
  for (int i = 0; i < 32; ++i) {
    const int kt = (i + kt0) & 31;
    const int col0 = kt * 64;
    gl_lds16(kh + (size_t)(col0 + srow) * 64 + swc, Kl + tid * 8);
    gl_lds16(vh + (size_t)srow * TSEQ + col0 + swc, Vl + tid * 8);
    __syncthreads();   // A: stage complete; prev store-phase Pf reads done
#pragma unroll
    for (int n = 0; n < 4; ++n) {
      const u16* kr = Kl + (n * 16 + l) * 64;
      s8v b0 = *(const s8v*)(kr + (g ^ lx) * 8);
      s8v b1 = *(const s8v*)(kr + ((4 + g) ^ lx) * 8);
      f4v s = {};
      s = MFMA16(b0, qf0, s);
      s = MFMA16(b1, qf1, s);
      f4v p;
#pragma unroll
      for (int r = 0; r < 4; ++r) p[r] = __expf(s[r] * scale) * inv;
      // P[q-row l][keys n*16+g*4 .. +4) for this wave
      *(f4v*)&Pf[prow * 76 + n * 16 + g * 4] = p;
    }
    // wave-local fence: Pf rows are wave-private here; drain this wave's
    // ds_writes before its cross-lane ds_reads (rule-18 form).
    asm volatile("s_waitcnt lgkmcnt(0)" ::: "memory");
    __builtin_amdgcn_sched_barrier(0);
    // PV for this 64-key tile: read P rows, pack bf16 on the fly
#pragma unroll
    for (int ks = 0; ks < 2; ++ks) {
      const float* pr = &Pf[prow * 76 + ks * 32 + g * 8];
      f4v r0 = *(const f4v*)pr;
      f4v r1 = *(const f4v*)(pr + 4);
      union { unsigned u[4]; s8v s; } pc;
      pc.u[0] = cvt_pk(r0[0], r0[1]);
      pc.u[1] = cvt_pk(r0[2], r0[3]);
      pc.u[2] = cvt_pk(r1[0], r1[1]);
      pc.u[3] = cvt_pk(r1[2], r1[3]);
      s8v pa = pc.s;
#pragma unroll
      for (int n4 = 0; n4 < 4; ++n4) {
        const u16* vr = Vl + (n4 * 16 + l) * 64;
        s8v bvv = *(const s8v*)(vr + ((ks * 4 + g) ^ lx) * 8);
        cacc[n4] = MFMA16(pa, bvv, cacc[n4]);
      }
    }
    __syncthreads();   // B: all waves' Pf visible; K/V + Pf reads done
    // store phase: 4 rounds x (32 rows x 256B contiguous per row)
#pragma unroll
    for (int r4 = 0; r4 < 4; ++r4) {
      const int rho = r4 * 32 + st_r;
      f4v pv_ = *(const f4v*)&Pf[rho * 76 + st_c];
      *(f4v*)(attn_h + (size_t)(qt * 128 + rho) * TSEQ + col0 + st_c) = pv_;
    }
  }
  // write ctx (flat layout == (B,T,D) row-major); C row = q-row = g*4+r
#pragma unroll
  for (int n4 = 0; n4 < 4; ++n4)
#pragma unroll
    for (int r = 0; r < 4; ++r)
      ctx[(size_t)hb * HB_ELEMS + (size_t)(row0 + g * 4 + r) * 64 + n4 * 16 + l] =
          cacc[n4][r];
}

// ---------------- residual + LayerNorm ----------------
__global__ void ln_kernel(const float* __restrict__ q, const float* __restrict__ ctx,
                          const float* __restrict__ gam, const float* __restrict__ bet,
                          float* __restrict__ out) {
  const int row = blockIdx.x;
  const int tid = threadIdx.x;
  const float* qr = q + (size_t)row * 1024;
  const float* cr = ctx + (size_t)row * 1024;
  float4 xq = *(const float4*)(qr + tid * 4);
  float4 xc = *(const float4*)(cr + tid * 4);
  float x0 = xq.x + xc.x, x1 = xq.y + xc.y, x2 = xq.z + xc.z, x3 = xq.w + xc.w;
  float s1 = x0 + x1 + x2 + x3;
  float s2 = x0 * x0 + x1 * x1 + x2 * x2 + x3 * x3;
#pragma unroll
  for (int off = 1; off < 64; off <<= 1) {
    s1 += __shfl_xor(s1, off);
    s2 += __shfl_xor(s2, off);
  }
  __shared__ float ra[4], rb[4];
  int w = tid >> 6, lane = tid & 63;
  if (lane == 0) { ra[w] = s1; rb[w] = s2; }
  __syncthreads();
  s1 = ra[0] + ra[1] + ra[2] + ra[3];
  s2 = rb[0] + rb[1] + rb[2] + rb[3];
  float mu = s1 * (1.0f / 1024.0f);
  float var = s2 * (1.0f / 1024.0f) - mu * mu;
  float rstd = rsqrtf(var + 1e-5f);
  float4 gv = *(const float4*)(gam + tid * 4);
  float4 bv = *(const float4*)(bet + tid * 4);
  float4 o;
  o.x = (x0 - mu) * rstd * gv.x + bv.x;
  o.y = (x1 - mu) * rstd * gv.y + bv.y;
  o.z = (x2 - mu) * rstd * gv.z + bv.z;
  o.w = (x3 - mu) * rstd * gv.w + bv.w;
  *(float4*)(out + (size_t)row * 1024 + tid * 4) = o;
}

extern "C" void kernel_launch(void* const* d_in, const int* in_sizes, int n_in,
                              void* d_out, int out_size, void* d_ws, size_t ws_size,
                              hipStream_t stream) {
  const float* q    = (const float*)d_in[0];
  const float* k    = (const float*)d_in[1];
  const float* v    = (const float*)d_in[2];
  const float* wq   = (const float*)d_in[3];
  const float* bq   = (const float*)d_in[4];
  const float* wk   = (const float*)d_in[5];
  const float* bk   = (const float*)d_in[6];
  const float* wv   = (const float*)d_in[7];
  const float* bv   = (const float*)d_in[8];
  const float* ln_g = (const float*)d_in[9];
  const float* ln_b = (const float*)d_in[10];

  char* ws = (char*)d_ws;
  u16* qbf  = (u16*)(ws);              // 3 x 8 MiB   bf16 inputs (q,k,v)
  u16* wbf  = (u16*)(ws + 25165824);   // 3 x 2 MiB   bf16 weights (contig w/ qbf)
  u16* qp   = (u16*)(ws + 31457280);   // 3 x 8 MiB   bf16 projections (qp,kp,vp)
  u16* vT   = (u16*)(ws + 56623104);   // 8 MiB       per-head transposed V
  float* ctx = (float*)(ws + 65011712); // 16 MiB     fp32 context

  float* out  = (float*)d_out;
  float* attn = out + 4194304;

  cvt_all<<<15360, 256, 0, stream>>>(q, k, v, wq, wk, wv, qbf);

  proj_gemm<<<dim3(8, 32, 3), 256, 0, stream>>>(qbf, wbf, bq, bk, bv, qp);

  vtrans<<<dim3(32, 32), 256, 0, stream>>>(qp + 8388608, vT);

  attn_fused<<<dim3(16, 32), 512, 0, stream>>>(qp, qp + 4194304, vT, attn, ctx);

  ln_kernel<<<4096, 256, 0, stream>>>(q, ctx, ln_g, ln_b, out);
}

// Round 21
// 213.548 us; speedup vs baseline: 1.0473x; 1.0415x over previous
//
#include <hip/hip_runtime.h>

typedef unsigned short u16;
typedef __attribute__((ext_vector_type(8))) short s8v;   // 8 x bf16 (4 VGPR)
typedef __attribute__((ext_vector_type(4))) float f4v;   // MFMA accum

#define MFMA16(a, b, c) __builtin_amdgcn_mfma_f32_16x16x32_bf16(a, b, c, 0, 0, 0)

#define TSEQ 2048
#define NTOK 4096          // B*T
#define HEADS 32           // H*B
#define HB_ELEMS 131072    // T*dh elems per head block

__device__ __forceinline__ unsigned cvt_pk(float lo, float hi) {
  unsigned r;
  asm("v_cvt_pk_bf16_f32 %0, %1, %2" : "=v"(r) : "v"(lo), "v"(hi));
  return r;
}

__device__ __forceinline__ void gl_lds16(const u16* g, u16* l) {
  __builtin_amdgcn_global_load_lds(
      (const __attribute__((address_space(1))) void*)g,
      (__attribute__((address_space(3))) void*)l, 16, 0, 0);
}

// ---------------- fused fp32 -> bf16 convert (all 6 tensors, one launch) -----
__global__ void cvt_all(const float* __restrict__ q, const float* __restrict__ k,
                        const float* __restrict__ v, const float* __restrict__ wq,
                        const float* __restrict__ wk, const float* __restrict__ wv,
                        u16* __restrict__ dst) {
  int i = (blockIdx.x * blockDim.x + threadIdx.x) * 4;
  const float* src; int off;
  if (i < 12582912) {
    int s = i >> 22; src = (s == 0) ? q : ((s == 1) ? k : v); off = i & 4194303;
  } else {
    int j = i - 12582912;
    int s = j >> 20; src = (s == 0) ? wq : ((s == 1) ? wk : wv); off = j & 1048575;
  }
  float4 val = *(const float4*)(src + off);
  uint2 o;
  o.x = cvt_pk(val.x, val.y);
  o.y = cvt_pk(val.z, val.w);
  *(uint2*)(dst + i) = o;
}

// ---------------- projection GEMM: C = A(4096x1024) * W(1024x1024)^T + bias ----
__launch_bounds__(256, 3)
__global__ void proj_gemm(const u16* __restrict__ Aall, const u16* __restrict__ Wall,
                          const float* __restrict__ bqp, const float* __restrict__ bkp,
                          const float* __restrict__ bvp, u16* __restrict__ Call) {
  const int z = blockIdx.z;
  const u16* A = Aall + (size_t)z * 4194304;
  const u16* W = Wall + (size_t)z * 1048576;
  u16* C = Call + (size_t)z * 4194304;
  const float* bias = (z == 0) ? bqp : ((z == 1) ? bkp : bvp);

  __shared__ __align__(16) u16 SH[17408];   // As[0..8K) Bs[8K..16K); T[128][136]
  u16* As = SH;
  u16* Bs = SH + 8192;

  const int tid = threadIdx.x;
  const int w = tid >> 6, lane = tid & 63, g = lane >> 4, l = lane & 15;
  const int wr = w >> 1, wc = w & 1;
  const int tr = blockIdx.y * 128, tc = blockIdx.x * 128;

  const int srow = tid >> 3;        // 0..31  (staging row within 32-row chunk)
  const int scol = (tid & 7) * 8;   // elem col within 64

  f4v acc[4][4] = {};

  for (int kt = 0; kt < 1024; kt += 64) {
#pragma unroll
    for (int c4 = 0; c4 < 4; ++c4) {
      gl_lds16(A + (size_t)(tr + c4 * 32 + srow) * 1024 + kt + scol,
               As + c4 * 2048 + tid * 8);
      gl_lds16(W + (size_t)(tc + c4 * 32 + srow) * 1024 + kt + scol,
               Bs + c4 * 2048 + tid * 8);
    }
    __syncthreads();
#pragma unroll
    for (int ks = 0; ks < 2; ++ks) {
      s8v a[4], bb[4];
#pragma unroll
      for (int m = 0; m < 4; ++m)
        a[m] = *(const s8v*)(As + (wr * 64 + m * 16 + l) * 64 + ks * 32 + g * 8);
#pragma unroll
      for (int n = 0; n < 4; ++n)
        bb[n] = *(const s8v*)(Bs + (wc * 64 + n * 16 + l) * 64 + ks * 32 + g * 8);
#pragma unroll
      for (int m = 0; m < 4; ++m)
#pragma unroll
        for (int n = 0; n < 4; ++n)
          acc[m][n] = MFMA16(a[m], bb[n], acc[m][n]);
    }
    __syncthreads();
  }
  // ---- epilogue: bias + bf16 pack into LDS tile T[t 128][d 136], then
  // coalesced 16B global stores.
  u16* T = SH;
#pragma unroll
  for (int m = 0; m < 4; ++m)
#pragma unroll
    for (int n = 0; n < 4; ++n) {
      int d = wc * 64 + n * 16 + l;
      float bv = bias[tc + d];
      unsigned c01 = cvt_pk(acc[m][n][0] + bv, acc[m][n][1] + bv);
      unsigned c23 = cvt_pk(acc[m][n][2] + bv, acc[m][n][3] + bv);
      int t0 = wr * 64 + m * 16 + g * 4;
      T[(t0 + 0) * 136 + d] = (u16)c01;
      T[(t0 + 1) * 136 + d] = (u16)(c01 >> 16);
      T[(t0 + 2) * 136 + d] = (u16)c23;
      T[(t0 + 3) * 136 + d] = (u16)(c23 >> 16);
    }
  __syncthreads();
#pragma unroll
  for (int it = 0; it < 8; ++it) {
    int t = it * 16 + (tid >> 4);
    int c8 = (tid & 15) * 8;
    *(s8v*)(C + (size_t)(tr + t) * 1024 + tc + c8) = *(const s8v*)&T[t * 136 + c8];
  }
}

// ---------------- per-head V transpose: vT[hb][d][t] = vp[hb][t][d] ----------
__global__ void vtrans(const u16* __restrict__ vp, u16* __restrict__ vT) {
  const int hb = blockIdx.y;
  const int t0 = blockIdx.x * 64;
  const int tid = threadIdx.x;
  __shared__ u16 tl[64][65];
  const u16* vph = vp + (size_t)hb * HB_ELEMS;
  u16* vth = vT + (size_t)hb * HB_ELEMS;
#pragma unroll
  for (int it = 0; it < 4; ++it) {
    int i = (tid + it * 256) * 4;
    int r = i >> 6, c = i & 63;
    *(ushort4*)&tl[r][c] = *(const ushort4*)(vph + (size_t)(t0 + r) * 64 + c);
  }
  __syncthreads();
#pragma unroll
  for (int it = 0; it < 4; ++it) {
    int i = (tid + it * 256) * 4;
    int d = i >> 6, j = i & 63;
    ushort4 o;
    o.x = tl[j + 0][d]; o.y = tl[j + 1][d]; o.z = tl[j + 2][d]; o.w = tl[j + 3][d];
    *(ushort4*)(vth + (size_t)d * TSEQ + t0 + j) = o;
  }
}

// ---------------- fused attention: counted-vmcnt pipeline -------------------
// grid: 512 blocks (16 qtiles x 32 heads, XCD-swizzled); 8 waves x 16 q-rows.
// Pass 2: K/V double-buffered, ONE barrier per iteration, counted vmcnt(4)
// so the 4 global attn stores stay in flight across the barrier (overlapping
// compute). Pf handoff is wave-private rows + wave-local lgkmcnt fence
// (R19/R20-proven; its absence was R15/R17/R18's failure). Wave-local store
// of each wave's OWN 16 rows (256B/row coalesced) needs no extra barrier.
__launch_bounds__(512, 2)
__global__ void attn_fused(const u16* __restrict__ qp, const u16* __restrict__ kp,
                           const u16* __restrict__ vT, float* __restrict__ attn,
                           float* __restrict__ ctx) {
  // XCD-bijective swizzle: all 16 q-tiles of a head share (hw & 7) -> same XCD
  const int hw = blockIdx.x + (blockIdx.y << 4);
  const int hb = (hw & 7) + ((hw >> 7) << 3);
  const int qt = (hw >> 3) & 15;

  const int tid = threadIdx.x;                    // 0..511
  const int w = tid >> 6, lane = tid & 63, g = lane >> 4, l = lane & 15;
  const int lx = l & 7;

  const u16* qh = qp + (size_t)hb * HB_ELEMS;
  const u16* kh = kp + (size_t)hb * HB_ELEMS;
  const u16* vh = vT + (size_t)hb * HB_ELEMS;

  // pass1: K[256][64] (32KB). pass2: K0[2] 16KB | V0[2] 16KB | Pf[128][76]
  // f32 38KB = 70KB total -> 2 blocks/CU.
  __shared__ __align__(16) u16 SH[35840];

  const int row0 = qt * 128 + w * 16;             // wave's 16 q-rows
  const float scale = 0.125f;                     // dh^-0.5

  // staging geometry: thread t covers row (t>>3), 16B chunk t&7
  const int srow = tid >> 3;                      // 0..63
  const int swc = ((tid & 7) ^ (srow & 7)) * 8;   // swizzled source col (elems)

  // Q as B-operand fragment: lane (g,l) holds Q[row0+l][ks*32+g*8 .. +8)
  s8v qf0 = *(const s8v*)(qh + (size_t)(row0 + l) * 64 + g * 8);
  s8v qf1 = *(const s8v*)(qh + (size_t)(row0 + l) * 64 + 32 + g * 8);

  // ---- pass 1: row sums of exp(score); swapped mfma(K,Q) => C col = q-row l
  float sum = 0.0f;
  for (int kt4 = 0; kt4 < 8; ++kt4) {
    const int c0 = kt4 * 256;
#pragma unroll
    for (int c4 = 0; c4 < 4; ++c4)
      gl_lds16(kh + (size_t)(c0 + c4 * 64 + srow) * 64 + swc,
               SH + c4 * 4096 + tid * 8);
    __syncthreads();
#pragma unroll
    for (int q4 = 0; q4 < 4; ++q4) {
#pragma unroll
      for (int n = 0; n < 4; ++n) {
        const u16* kr = SH + q4 * 4096 + (n * 16 + l) * 64;
        s8v b0 = *(const s8v*)(kr + (g ^ lx) * 8);
        s8v b1 = *(const s8v*)(kr + ((4 + g) ^ lx) * 8);
        f4v s = {};
        s = MFMA16(b0, qf0, s);
        s = MFMA16(b1, qf1, s);
        sum += __expf(s[0] * scale) + __expf(s[1] * scale)
             + __expf(s[2] * scale) + __expf(s[3] * scale);
      }
    }
    __syncthreads();
  }
  // reduce across the 4 g-groups holding the same q-row l
  sum += __shfl_xor(sum, 16);
  sum += __shfl_xor(sum, 32);
  const float inv = 1.0f / sum;
  __syncthreads();   // pass-1 SH reads done before pass-2 staging overwrites

  // ---- pass 2 ----
  u16* K0 = SH;                       // [2][64][64] bf16 swizzled (16 KB)
  u16* V0 = SH + 8192;                // [2][64][64] bf16 swizzled (16 KB)
  float* Pf = (float*)(SH + 16384);   // [128][76] f32 P tile (38 KB)

#define STAGE2(b, kt_) do { const int c0_ = (kt_) * 64;                          \
    gl_lds16(kh + (size_t)(c0_ + srow) * 64 + swc, K0 + (b) * 4096 + tid * 8);   \
    gl_lds16(vh + (size_t)srow * TSEQ + c0_ + swc, V0 + (b) * 4096 + tid * 8);   \
  } while (0)

  f4v cacc[4] = {};
  float* attn_h = attn + (size_t)hb * TSEQ * TSEQ;
  const int kt0 = (qt * 2 + ((hw >> 7) << 3)) & 31;  // column-window rotation
  const int prow = w * 16 + l;                    // this lane's P row
  const int sr4 = lane >> 4;                      // store row-within-4group
  const int sc = (lane & 15) * 4;                 // store float col

  STAGE2(0, kt0);
  asm volatile("s_waitcnt vmcnt(0)" ::: "memory");
  __builtin_amdgcn_sched_barrier(0);
  __builtin_amdgcn_s_barrier();

  for (int i = 0; i < 32; ++i) {
    const int cur = i & 1;
    const int col0 = ((i + kt0) & 31) * 64;
    const u16* Kl = K0 + cur * 4096;
    const u16* Vl = V0 + cur * 4096;
    // issue next stage first: overlaps entire compute phase
    if (i < 31) STAGE2(cur ^ 1, (i + 1 + kt0) & 31);
#pragma unroll
    for (int n = 0; n < 4; ++n) {
      const u16* kr = Kl + (n * 16 + l) * 64;
      s8v b0 = *(const s8v*)(kr + (g ^ lx) * 8);
      s8v b1 = *(const s8v*)(kr + ((4 + g) ^ lx) * 8);
      f4v s = {};
      s = MFMA16(b0, qf0, s);
      s = MFMA16(b1, qf1, s);
      f4v p;
#pragma unroll
      for (int r = 0; r < 4; ++r) p[r] = __expf(s[r] * scale) * inv;
      *(f4v*)&Pf[prow * 76 + n * 16 + g * 4] = p;
    }
    // wave-local fence: drain this wave's Pf ds_writes before cross-lane reads
    asm volatile("s_waitcnt lgkmcnt(0)" ::: "memory");
    __builtin_amdgcn_sched_barrier(0);
    // PV: read wave-private P rows, pack bf16 on the fly
#pragma unroll
    for (int ks = 0; ks < 2; ++ks) {
      const float* pr = &Pf[prow * 76 + ks * 32 + g * 8];
      f4v r0 = *(const f4v*)pr;
      f4v r1 = *(const f4v*)(pr + 4);
      union { unsigned u[4]; s8v s; } pc;
      pc.u[0] = cvt_pk(r0[0], r0[1]);
      pc.u[1] = cvt_pk(r0[2], r0[3]);
      pc.u[2] = cvt_pk(r1[0], r1[1]);
      pc.u[3] = cvt_pk(r1[2], r1[3]);
      s8v pa = pc.s;
#pragma unroll
      for (int n4 = 0; n4 < 4; ++n4) {
        const u16* vr = Vl + (n4 * 16 + l) * 64;
        s8v bvv = *(const s8v*)(vr + ((ks * 4 + g) ^ lx) * 8);
        cacc[n4] = MFMA16(pa, bvv, cacc[n4]);
      }
    }
    // wave-local store: wave w flushes its OWN 16 rows (fence above covers
    // the cross-lane Pf reads; rows are wave-private). 256B/row coalesced.
#pragma unroll
    for (int r4 = 0; r4 < 4; ++r4) {
      const int row = w * 16 + r4 * 4 + sr4;
      f4v pv_ = *(const f4v*)&Pf[row * 76 + sc];
      *(f4v*)(attn_h + (size_t)(qt * 128 + row) * TSEQ + col0 + sc) = pv_;
    }
    if (i < 31) {
      // drain own ds reads (Kl/Vl/Pf) so other waves may overwrite post-
      // barrier; vmcnt(4): retires the 2 stage loads (issue order: stage
      // then 4 stores -> 4 newest outstanding are this iter's stores,
      // which REMAIN IN FLIGHT across the barrier).
      asm volatile("s_waitcnt lgkmcnt(0)" ::: "memory");
      asm volatile("s_waitcnt vmcnt(4)" ::: "memory");
      __builtin_amdgcn_sched_barrier(0);
      __builtin_amdgcn_s_barrier();
    }
  }
#undef STAGE2
  // write ctx (flat layout == (B,T,D) row-major); C row = q-row = g*4+r
#pragma unroll
  for (int n4 = 0; n4 < 4; ++n4)
#pragma unroll
    for (int r = 0; r < 4; ++r)
      ctx[(size_t)hb * HB_ELEMS + (size_t)(row0 + g * 4 + r) * 64 + n4 * 16 + l] =
          cacc[n4][r];
}

// ---------------- residual + LayerNorm ----------------
__global__ void ln_kernel(const float* __restrict__ q, const float* __restrict__ ctx,
                          const float* __restrict__ gam, const float* __restrict__ bet,
                          float* __restrict__ out) {
  const int row = blockIdx.x;
  const int tid = threadIdx.x;
  const float* qr = q + (size_t)row * 1024;
  const float* cr = ctx + (size_t)row * 1024;
  float4 xq = *(const float4*)(qr + tid * 4);
  float4 xc = *(const float4*)(cr + tid * 4);
  float x0 = xq.x + xc.x, x1 = xq.y + xc.y, x2 = xq.z + xc.z, x3 = xq.w + xc.w;
  float s1 = x0 + x1 + x2 + x3;
  float s2 = x0 * x0 + x1 * x1 + x2 * x2 + x3 * x3;
#pragma unroll
  for (int off = 1; off < 64; off <<= 1) {
    s1 += __shfl_xor(s1, off);
    s2 += __shfl_xor(s2, off);
  }
  __shared__ float ra[4], rb[4];
  int w = tid >> 6, lane = tid & 63;
  if (lane == 0) { ra[w] = s1; rb[w] = s2; }
  __syncthreads();
  s1 = ra[0] + ra[1] + ra[2] + ra[3];
  s2 = rb[0] + rb[1] + rb[2] + rb[3];
  float mu = s1 * (1.0f / 1024.0f);
  float var = s2 * (1.0f / 1024.0f) - mu * mu;
  float rstd = rsqrtf(var + 1e-5f);
  float4 gv = *(const float4*)(gam + tid * 4);
  float4 bv = *(const float4*)(bet + tid * 4);
  float4 o;
  o.x = (x0 - mu) * rstd * gv.x + bv.x;
  o.y = (x1 - mu) * rstd * gv.y + bv.y;
  o.z = (x2 - mu) * rstd * gv.z + bv.z;
  o.w = (x3 - mu) * rstd * gv.w + bv.w;
  *(float4*)(out + (size_t)row * 1024 + tid * 4) = o;
}

extern "C" void kernel_launch(void* const* d_in, const int* in_sizes, int n_in,
                              void* d_out, int out_size, void* d_ws, size_t ws_size,
                              hipStream_t stream) {
  const float* q    = (const float*)d_in[0];
  const float* k    = (const float*)d_in[1];
  const float* v    = (const float*)d_in[2];
  const float* wq   = (const float*)d_in[3];
  const float* bq   = (const float*)d_in[4];
  const float* wk   = (const float*)d_in[5];
  const float* bk   = (const float*)d_in[6];
  const float* wv   = (const float*)d_in[7];
  const float* bv   = (const float*)d_in[8];
  const float* ln_g = (const float*)d_in[9];
  const float* ln_b = (const float*)d_in[10];

  char* ws = (char*)d_ws;
  u16* qbf  = (u16*)(ws);              // 3 x 8 MiB   bf16 inputs (q,k,v)
  u16* wbf  = (u16*)(ws + 25165824);   // 3 x 2 MiB   bf16 weights (contig w/ qbf)
  u16* qp   = (u16*)(ws + 31457280);   // 3 x 8 MiB   bf16 projections (qp,kp,vp)
  u16* vT   = (u16*)(ws + 56623104);   // 8 MiB       per-head transposed V
  float* ctx = (float*)(ws + 65011712); // 16 MiB     fp32 context

  float* out  = (float*)d_out;
  float* attn = out + 4194304;

  cvt_all<<<15360, 256, 0, stream>>>(q, k, v, wq, wk, wv, qbf);

  proj_gemm<<<dim3(8, 32, 3), 256, 0, stream>>>(qbf, wbf, bq, bk, bv, qp);

  vtrans<<<dim3(32, 32), 256, 0, stream>>>(qp + 8388608, vT);

  attn_fused<<<dim3(16, 32), 512, 0, stream>>>(qp, qp + 4194304, vT, attn, ctx);

  ln_kernel<<<4096, 256, 0, stream>>>(q, ctx, ln_g, ln_b, out);
}

// Round 22
// 210.075 us; speedup vs baseline: 1.0646x; 1.0165x over previous
//
#include <hip/hip_runtime.h>

typedef unsigned short u16;
typedef __attribute__((ext_vector_type(8))) short s8v;   // 8 x bf16 (4 VGPR)
typedef __attribute__((ext_vector_type(4))) float f4v;   // MFMA accum

#define MFMA16(a, b, c) __builtin_amdgcn_mfma_f32_16x16x32_bf16(a, b, c, 0, 0, 0)

#define TSEQ 2048
#define NTOK 4096          // B*T
#define HEADS 32           // H*B
#define HB_ELEMS 131072    // T*dh elems per head block

__device__ __forceinline__ unsigned cvt_pk(float lo, float hi) {
  unsigned r;
  asm("v_cvt_pk_bf16_f32 %0, %1, %2" : "=v"(r) : "v"(lo), "v"(hi));
  return r;
}

__device__ __forceinline__ void gl_lds16(const u16* g, u16* l) {
  __builtin_amdgcn_global_load_lds(
      (const __attribute__((address_space(1))) void*)g,
      (__attribute__((address_space(3))) void*)l, 16, 0, 0);
}

// ---------------- fused fp32 -> bf16 convert (all 6 tensors, one launch) -----
__global__ void cvt_all(const float* __restrict__ q, const float* __restrict__ k,
                        const float* __restrict__ v, const float* __restrict__ wq,
                        const float* __restrict__ wk, const float* __restrict__ wv,
                        u16* __restrict__ dst) {
  int i = (blockIdx.x * blockDim.x + threadIdx.x) * 4;
  const float* src; int off;
  if (i < 12582912) {
    int s = i >> 22; src = (s == 0) ? q : ((s == 1) ? k : v); off = i & 4194303;
  } else {
    int j = i - 12582912;
    int s = j >> 20; src = (s == 0) ? wq : ((s == 1) ? wk : wv); off = j & 1048575;
  }
  float4 val = *(const float4*)(src + off);
  uint2 o;
  o.x = cvt_pk(val.x, val.y);
  o.y = cvt_pk(val.z, val.w);
  *(uint2*)(dst + i) = o;
}

// ---------------- projection GEMM: C = A(4096x1024) * W(1024x1024)^T + bias ----
__launch_bounds__(256, 3)
__global__ void proj_gemm(const u16* __restrict__ Aall, const u16* __restrict__ Wall,
                          const float* __restrict__ bqp, const float* __restrict__ bkp,
                          const float* __restrict__ bvp, u16* __restrict__ Call) {
  const int z = blockIdx.z;
  const u16* A = Aall + (size_t)z * 4194304;
  const u16* W = Wall + (size_t)z * 1048576;
  u16* C = Call + (size_t)z * 4194304;
  const float* bias = (z == 0) ? bqp : ((z == 1) ? bkp : bvp);

  __shared__ __align__(16) u16 SH[17408];   // As[0..8K) Bs[8K..16K); T[128][136]
  u16* As = SH;
  u16* Bs = SH + 8192;

  const int tid = threadIdx.x;
  const int w = tid >> 6, lane = tid & 63, g = lane >> 4, l = lane & 15;
  const int wr = w >> 1, wc = w & 1;
  const int tr = blockIdx.y * 128, tc = blockIdx.x * 128;

  const int srow = tid >> 3;        // 0..31  (staging row within 32-row chunk)
  const int scol = (tid & 7) * 8;   // elem col within 64

  f4v acc[4][4] = {};

  for (int kt = 0; kt < 1024; kt += 64) {
#pragma unroll
    for (int c4 = 0; c4 < 4; ++c4) {
      gl_lds16(A + (size_t)(tr + c4 * 32 + srow) * 1024 + kt + scol,
               As + c4 * 2048 + tid * 8);
      gl_lds16(W + (size_t)(tc + c4 * 32 + srow) * 1024 + kt + scol,
               Bs + c4 * 2048 + tid * 8);
    }
    __syncthreads();
#pragma unroll
    for (int ks = 0; ks < 2; ++ks) {
      s8v a[4], bb[4];
#pragma unroll
      for (int m = 0; m < 4; ++m)
        a[m] = *(const s8v*)(As + (wr * 64 + m * 16 + l) * 64 + ks * 32 + g * 8);
#pragma unroll
      for (int n = 0; n < 4; ++n)
        bb[n] = *(const s8v*)(Bs + (wc * 64 + n * 16 + l) * 64 + ks * 32 + g * 8);
#pragma unroll
      for (int m = 0; m < 4; ++m)
#pragma unroll
        for (int n = 0; n < 4; ++n)
          acc[m][n] = MFMA16(a[m], bb[n], acc[m][n]);
    }
    __syncthreads();
  }
  // ---- epilogue: bias + bf16 pack into LDS tile T[t 128][d 136], then
  // coalesced 16B global stores.
  u16* T = SH;
#pragma unroll
  for (int m = 0; m < 4; ++m)
#pragma unroll
    for (int n = 0; n < 4; ++n) {
      int d = wc * 64 + n * 16 + l;
      float bv = bias[tc + d];
      unsigned c01 = cvt_pk(acc[m][n][0] + bv, acc[m][n][1] + bv);
      unsigned c23 = cvt_pk(acc[m][n][2] + bv, acc[m][n][3] + bv);
      int t0 = wr * 64 + m * 16 + g * 4;
      T[(t0 + 0) * 136 + d] = (u16)c01;
      T[(t0 + 1) * 136 + d] = (u16)(c01 >> 16);
      T[(t0 + 2) * 136 + d] = (u16)c23;
      T[(t0 + 3) * 136 + d] = (u16)(c23 >> 16);
    }
  __syncthreads();
#pragma unroll
  for (int it = 0; it < 8; ++it) {
    int t = it * 16 + (tid >> 4);
    int c8 = (tid & 15) * 8;
    *(s8v*)(C + (size_t)(tr + t) * 1024 + tc + c8) = *(const s8v*)&T[t * 136 + c8];
  }
}

// ---------------- per-head V transpose: vT[hb][d][t] = vp[hb][t][d] ----------
__global__ void vtrans(const u16* __restrict__ vp, u16* __restrict__ vT) {
  const int hb = blockIdx.y;
  const int t0 = blockIdx.x * 64;
  const int tid = threadIdx.x;
  __shared__ u16 tl[64][65];
  const u16* vph = vp + (size_t)hb * HB_ELEMS;
  u16* vth = vT + (size_t)hb * HB_ELEMS;
#pragma unroll
  for (int it = 0; it < 4; ++it) {
    int i = (tid + it * 256) * 4;
    int r = i >> 6, c = i & 63;
    *(ushort4*)&tl[r][c] = *(const ushort4*)(vph + (size_t)(t0 + r) * 64 + c);
  }
  __syncthreads();
#pragma unroll
  for (int it = 0; it < 4; ++it) {
    int i = (tid + it * 256) * 4;
    int d = i >> 6, j = i & 63;
    ushort4 o;
    o.x = tl[j + 0][d]; o.y = tl[j + 1][d]; o.z = tl[j + 2][d]; o.w = tl[j + 3][d];
    *(ushort4*)(vth + (size_t)d * TSEQ + t0 + j) = o;
  }
}

// ---------------- fused attention: counted-vmcnt pipeline (both passes) -----
// grid: 512 blocks (16 qtiles x 32 heads, XCD-swizzled); 8 waves x 16 q-rows.
// Pass 1: K double-buffered (2x32KB), 256-key rounds, ONE barrier per round —
// staging overlaps compute; barrier count 16 -> 8.
// Pass 2 (R21-proven): K/V dbuf, one barrier/iter, counted vmcnt(4) so attn
// stores stay in flight across barriers; Pf handoff = wave-private rows +
// wave-local lgkmcnt fence.
__launch_bounds__(512, 2)
__global__ void attn_fused(const u16* __restrict__ qp, const u16* __restrict__ kp,
                           const u16* __restrict__ vT, float* __restrict__ attn,
                           float* __restrict__ ctx) {
  // XCD-bijective swizzle: all 16 q-tiles of a head share (hw & 7) -> same XCD
  const int hw = blockIdx.x + (blockIdx.y << 4);
  const int hb = (hw & 7) + ((hw >> 7) << 3);
  const int qt = (hw >> 3) & 15;

  const int tid = threadIdx.x;                    // 0..511
  const int w = tid >> 6, lane = tid & 63, g = lane >> 4, l = lane & 15;
  const int lx = l & 7;

  const u16* qh = qp + (size_t)hb * HB_ELEMS;
  const u16* kh = kp + (size_t)hb * HB_ELEMS;
  const u16* vh = vT + (size_t)hb * HB_ELEMS;

  // pass1: Ka/Kb dbuf 2x32KB. pass2: K0[2] 16KB | V0[2] 16KB | Pf 38KB = 70KB.
  __shared__ __align__(16) u16 SH[35840];

  const int row0 = qt * 128 + w * 16;             // wave's 16 q-rows
  const float scale = 0.125f;                     // dh^-0.5

  // staging geometry: thread t covers row (t>>3), 16B chunk t&7
  const int srow = tid >> 3;                      // 0..63
  const int swc = ((tid & 7) ^ (srow & 7)) * 8;   // swizzled source col (elems)

  // Q as B-operand fragment: lane (g,l) holds Q[row0+l][ks*32+g*8 .. +8)
  s8v qf0 = *(const s8v*)(qh + (size_t)(row0 + l) * 64 + g * 8);
  s8v qf1 = *(const s8v*)(qh + (size_t)(row0 + l) * 64 + 32 + g * 8);

  // ---- pass 1: row sums of exp(score); K double-buffered, 1 barrier/round --
#define STAGE1(buf, kt4_) do { const int c0_ = (kt4_) * 256;                    \
    _Pragma("unroll")                                                           \
    for (int c4 = 0; c4 < 4; ++c4)                                              \
      gl_lds16(kh + (size_t)(c0_ + c4 * 64 + srow) * 64 + swc,                  \
               (buf) + c4 * 4096 + tid * 8);                                    \
  } while (0)

  u16* Ka = SH;            // 32 KB
  u16* Kb = SH + 16384;    // 32 KB

  float sum = 0.0f;
  STAGE1(Ka, 0);
  asm volatile("s_waitcnt vmcnt(0)" ::: "memory");
  __builtin_amdgcn_sched_barrier(0);
  __builtin_amdgcn_s_barrier();
  for (int kt4 = 0; kt4 < 8; ++kt4) {
    const u16* kbuf = (kt4 & 1) ? Kb : Ka;
    if (kt4 < 7) STAGE1((kt4 & 1) ? Ka : Kb, kt4 + 1);
#pragma unroll
    for (int q4 = 0; q4 < 4; ++q4) {
#pragma unroll
      for (int n = 0; n < 4; ++n) {
        const u16* kr = kbuf + q4 * 4096 + (n * 16 + l) * 64;
        s8v b0 = *(const s8v*)(kr + (g ^ lx) * 8);
        s8v b1 = *(const s8v*)(kr + ((4 + g) ^ lx) * 8);
        f4v s = {};
        s = MFMA16(b0, qf0, s);
        s = MFMA16(b1, qf1, s);
        sum += __expf(s[0] * scale) + __expf(s[1] * scale)
             + __expf(s[2] * scale) + __expf(s[3] * scale);
      }
    }
    // reads of kbuf retired + next stage landed before crossing
    asm volatile("s_waitcnt lgkmcnt(0)" ::: "memory");
    asm volatile("s_waitcnt vmcnt(0)" ::: "memory");
    __builtin_amdgcn_sched_barrier(0);
    __builtin_amdgcn_s_barrier();
  }
#undef STAGE1
  // reduce across the 4 g-groups holding the same q-row l
  sum += __shfl_xor(sum, 16);
  sum += __shfl_xor(sum, 32);
  const float inv = 1.0f / sum;

  // ---- pass 2 (R21-proven counted-vmcnt pipeline) ----
  u16* K0 = SH;                       // [2][64][64] bf16 swizzled (16 KB)
  u16* V0 = SH + 8192;                // [2][64][64] bf16 swizzled (16 KB)
  float* Pf = (float*)(SH + 16384);   // [128][76] f32 P tile (38 KB)

#define STAGE2(b, kt_) do { const int c0_ = (kt_) * 64;                          \
    gl_lds16(kh + (size_t)(c0_ + srow) * 64 + swc, K0 + (b) * 4096 + tid * 8);   \
    gl_lds16(vh + (size_t)srow * TSEQ + c0_ + swc, V0 + (b) * 4096 + tid * 8);   \
  } while (0)

  f4v cacc[4] = {};
  float* attn_h = attn + (size_t)hb * TSEQ * TSEQ;
  const int kt0 = (qt * 2 + ((hw >> 7) << 3)) & 31;  // column-window rotation
  const int prow = w * 16 + l;                    // this lane's P row
  const int sr4 = lane >> 4;                      // store row-within-4group
  const int sc = (lane & 15) * 4;                 // store float col

  STAGE2(0, kt0);
  asm volatile("s_waitcnt vmcnt(0)" ::: "memory");
  __builtin_amdgcn_sched_barrier(0);
  __builtin_amdgcn_s_barrier();

  for (int i = 0; i < 32; ++i) {
    const int cur = i & 1;
    const int col0 = ((i + kt0) & 31) * 64;
    const u16* Kl = K0 + cur * 4096;
    const u16* Vl = V0 + cur * 4096;
    // issue next stage first: overlaps entire compute phase
    if (i < 31) STAGE2(cur ^ 1, (i + 1 + kt0) & 31);
#pragma unroll
    for (int n = 0; n < 4; ++n) {
      const u16* kr = Kl + (n * 16 + l) * 64;
      s8v b0 = *(const s8v*)(kr + (g ^ lx) * 8);
      s8v b1 = *(const s8v*)(kr + ((4 + g) ^ lx) * 8);
      f4v s = {};
      s = MFMA16(b0, qf0, s);
      s = MFMA16(b1, qf1, s);
      f4v p;
#pragma unroll
      for (int r = 0; r < 4; ++r) p[r] = __expf(s[r] * scale) * inv;
      *(f4v*)&Pf[prow * 76 + n * 16 + g * 4] = p;
    }
    // wave-local fence: drain this wave's Pf ds_writes before cross-lane reads
    asm volatile("s_waitcnt lgkmcnt(0)" ::: "memory");
    __builtin_amdgcn_sched_barrier(0);
    // PV: read wave-private P rows, pack bf16 on the fly
#pragma unroll
    for (int ks = 0; ks < 2; ++ks) {
      const float* pr = &Pf[prow * 76 + ks * 32 + g * 8];
      f4v r0 = *(const f4v*)pr;
      f4v r1 = *(const f4v*)(pr + 4);
      union { unsigned u[4]; s8v s; } pc;
      pc.u[0] = cvt_pk(r0[0], r0[1]);
      pc.u[1] = cvt_pk(r0[2], r0[3]);
      pc.u[2] = cvt_pk(r1[0], r1[1]);
      pc.u[3] = cvt_pk(r1[2], r1[3]);
      s8v pa = pc.s;
#pragma unroll
      for (int n4 = 0; n4 < 4; ++n4) {
        const u16* vr = Vl + (n4 * 16 + l) * 64;
        s8v bvv = *(const s8v*)(vr + ((ks * 4 + g) ^ lx) * 8);
        cacc[n4] = MFMA16(pa, bvv, cacc[n4]);
      }
    }
    // wave-local store: wave w flushes its OWN 16 rows (fence above covers
    // the cross-lane Pf reads; rows are wave-private). 256B/row coalesced.
#pragma unroll
    for (int r4 = 0; r4 < 4; ++r4) {
      const int row = w * 16 + r4 * 4 + sr4;
      f4v pv_ = *(const f4v*)&Pf[row * 76 + sc];
      *(f4v*)(attn_h + (size_t)(qt * 128 + row) * TSEQ + col0 + sc) = pv_;
    }
    if (i < 31) {
      // drain own ds reads (Kl/Vl/Pf) so other waves may overwrite post-
      // barrier; vmcnt(4): retires the 2 stage loads (issue order: stage
      // then 4 stores -> 4 newest outstanding are this iter's stores,
      // which REMAIN IN FLIGHT across the barrier).
      asm volatile("s_waitcnt lgkmcnt(0)" ::: "memory");
      asm volatile("s_waitcnt vmcnt(4)" ::: "memory");
      __builtin_amdgcn_sched_barrier(0);
      __builtin_amdgcn_s_barrier();
    }
  }
#undef STAGE2
  // write ctx (flat layout == (B,T,D) row-major); C row = q-row = g*4+r
#pragma unroll
  for (int n4 = 0; n4 < 4; ++n4)
#pragma unroll
    for (int r = 0; r < 4; ++r)
      ctx[(size_t)hb * HB_ELEMS + (size_t)(row0 + g * 4 + r) * 64 + n4 * 16 + l] =
          cacc[n4][r];
}

// ---------------- residual + LayerNorm ----------------
__global__ void ln_kernel(const float* __restrict__ q, const float* __restrict__ ctx,
                          const float* __restrict__ gam, const float* __restrict__ bet,
                          float* __restrict__ out) {
  const int row = blockIdx.x;
  const int tid = threadIdx.x;
  const float* qr = q + (size_t)row * 1024;
  const float* cr = ctx + (size_t)row * 1024;
  float4 xq = *(const float4*)(qr + tid * 4);
  float4 xc = *(const float4*)(cr + tid * 4);
  float x0 = xq.x + xc.x, x1 = xq.y + xc.y, x2 = xq.z + xc.z, x3 = xq.w + xc.w;
  float s1 = x0 + x1 + x2 + x3;
  float s2 = x0 * x0 + x1 * x1 + x2 * x2 + x3 * x3;
#pragma unroll
  for (int off = 1; off < 64; off <<= 1) {
    s1 += __shfl_xor(s1, off);
    s2 += __shfl_xor(s2, off);
  }
  __shared__ float ra[4], rb[4];
  int w = tid >> 6, lane = tid & 63;
  if (lane == 0) { ra[w] = s1; rb[w] = s2; }
  __syncthreads();
  s1 = ra[0] + ra[1] + ra[2] + ra[3];
  s2 = rb[0] + rb[1] + rb[2] + rb[3];
  float mu = s1 * (1.0f / 1024.0f);
  float var = s2 * (1.0f / 1024.0f) - mu * mu;
  float rstd = rsqrtf(var + 1e-5f);
  float4 gv = *(const float4*)(gam + tid * 4);
  float4 bv = *(const float4*)(bet + tid * 4);
  float4 o;
  o.x = (x0 - mu) * rstd * gv.x + bv.x;
  o.y = (x1 - mu) * rstd * gv.y + bv.y;
  o.z = (x2 - mu) * rstd * gv.z + bv.z;
  o.w = (x3 - mu) * rstd * gv.w + bv.w;
  *(float4*)(out + (size_t)row * 1024 + tid * 4) = o;
}

extern "C" void kernel_launch(void* const* d_in, const int* in_sizes, int n_in,
                              void* d_out, int out_size, void* d_ws, size_t ws_size,
                              hipStream_t stream) {
  const float* q    = (const float*)d_in[0];
  const float* k    = (const float*)d_in[1];
  const float* v    = (const float*)d_in[2];
  const float* wq   = (const float*)d_in[3];
  const float* bq   = (const float*)d_in[4];
  const float* wk   = (const float*)d_in[5];
  const float* bk   = (const float*)d_in[6];
  const float* wv   = (const float*)d_in[7];
  const float* bv   = (const float*)d_in[8];
  const float* ln_g = (const float*)d_in[9];
  const float* ln_b = (const float*)d_in[10];

  char* ws = (char*)d_ws;
  u16* qbf  = (u16*)(ws);              // 3 x 8 MiB   bf16 inputs (q,k,v)
  u16* wbf  = (u16*)(ws + 25165824);   // 3 x 2 MiB   bf16 weights (contig w/ qbf)
  u16* qp   = (u16*)(ws + 31457280);   // 3 x 8 MiB   bf16 projections (qp,kp,vp)
  u16* vT   = (u16*)(ws + 56623104);   // 8 MiB       per-head transposed V
  float* ctx = (float*)(ws + 65011712); // 16 MiB     fp32 context

  float* out  = (float*)d_out;
  float* attn = out + 4194304;

  cvt_all<<<15360, 256, 0, stream>>>(q, k, v, wq, wk, wv, qbf);

  proj_gemm<<<dim3(8, 32, 3), 256, 0, stream>>>(qbf, wbf, bq, bk, bv, qp);

  vtrans<<<dim3(32, 32), 256, 0, stream>>>(qp + 8388608, vT);

  attn_fused<<<dim3(16, 32), 512, 0, stream>>>(qp, qp + 4194304, vT, attn, ctx);

  ln_kernel<<<4096, 256, 0, stream>>>(q, ctx, ln_g, ln_b, out);
}

// Round 23
// 209.828 us; speedup vs baseline: 1.0659x; 1.0012x over previous
//
#include <hip/hip_runtime.h>

typedef unsigned short u16;
typedef __attribute__((ext_vector_type(8))) short s8v;   // 8 x bf16 (4 VGPR)
typedef __attribute__((ext_vector_type(4))) float f4v;   // MFMA accum

#define MFMA16(a, b, c) __builtin_amdgcn_mfma_f32_16x16x32_bf16(a, b, c, 0, 0, 0)

#define TSEQ 2048
#define NTOK 4096          // B*T
#define HEADS 32           // H*B
#define HB_ELEMS 131072    // T*dh elems per head block

__device__ __forceinline__ unsigned cvt_pk(float lo, float hi) {
  unsigned r;
  asm("v_cvt_pk_bf16_f32 %0, %1, %2" : "=v"(r) : "v"(lo), "v"(hi));
  return r;
}

__device__ __forceinline__ void gl_lds16(const u16* g, u16* l) {
  __builtin_amdgcn_global_load_lds(
      (const __attribute__((address_space(1))) void*)g,
      (__attribute__((address_space(3))) void*)l, 16, 0, 0);
}

// ---------------- fused fp32 -> bf16 convert (all 6 tensors, one launch) -----
__global__ void cvt_all(const float* __restrict__ q, const float* __restrict__ k,
                        const float* __restrict__ v, const float* __restrict__ wq,
                        const float* __restrict__ wk, const float* __restrict__ wv,
                        u16* __restrict__ dst) {
  int i = (blockIdx.x * blockDim.x + threadIdx.x) * 4;
  const float* src; int off;
  if (i < 12582912) {
    int s = i >> 22; src = (s == 0) ? q : ((s == 1) ? k : v); off = i & 4194303;
  } else {
    int j = i - 12582912;
    int s = j >> 20; src = (s == 0) ? wq : ((s == 1) ? wk : wv); off = j & 1048575;
  }
  float4 val = *(const float4*)(src + off);
  uint2 o;
  o.x = cvt_pk(val.x, val.y);
  o.y = cvt_pk(val.z, val.w);
  *(uint2*)(dst + i) = o;
}

// ---------------- projection GEMM: C = A(4096x1024) * W(1024x1024)^T + bias ----
// K-step 32, double-buffered staging (one barrier per iter; stage overlaps
// compute), XOR-swizzled A/B tiles (pre-swizzled global source + swizzled
// frag read, rule-21) removing the 16-way bank conflict of the old layout.
__launch_bounds__(256, 3)
__global__ void proj_gemm(const u16* __restrict__ Aall, const u16* __restrict__ Wall,
                          const float* __restrict__ bqp, const float* __restrict__ bkp,
                          const float* __restrict__ bvp, u16* __restrict__ Call) {
  const int z = blockIdx.z;
  const u16* A = Aall + (size_t)z * 4194304;
  const u16* W = Wall + (size_t)z * 1048576;
  u16* C = Call + (size_t)z * 4194304;
  const float* bias = (z == 0) ? bqp : ((z == 1) ? bkp : bvp);

  // staging: buf[2] x (A 4096 + B 4096) u16 = 32KB; T[128][136] aliases (34.8KB)
  __shared__ __align__(16) u16 SH[17408];

  const int tid = threadIdx.x;
  const int w = tid >> 6, lane = tid & 63, g = lane >> 4, l = lane & 15;
  const int wr = w >> 1, wc = w & 1;
  const int tr = blockIdx.y * 128, tc = blockIdx.x * 128;

  // staging geometry (128 rows x 32 cols per tile, 2 halves of 64 rows):
  // thread t covers row c2*64 + (t>>2), physical 16B chunk t&3; the DATA
  // placed there is logical chunk (t&3)^(row&3)  (pre-swizzled source).
  const int srow = tid >> 2;                    // 0..63
  const int swc = ((tid & 3) ^ (srow & 3)) * 8; // swizzled source col (elems)
  const int lx3 = l & 3;

#define PSTAGE(buf, kt_) do {                                                   \
    _Pragma("unroll")                                                           \
    for (int c2 = 0; c2 < 2; ++c2) {                                            \
      gl_lds16(A + (size_t)(tr + c2 * 64 + srow) * 1024 + (kt_) + swc,          \
               (buf) + c2 * 2048 + tid * 8);                                    \
      gl_lds16(W + (size_t)(tc + c2 * 64 + srow) * 1024 + (kt_) + swc,          \
               (buf) + 4096 + c2 * 2048 + tid * 8);                             \
    }                                                                           \
  } while (0)

  f4v acc[4][4] = {};

  PSTAGE(SH, 0);
  asm volatile("s_waitcnt vmcnt(0)" ::: "memory");
  __builtin_amdgcn_sched_barrier(0);
  __builtin_amdgcn_s_barrier();

  for (int i = 0; i < 32; ++i) {
    u16* buf = SH + (i & 1) * 8192;
    if (i < 31) PSTAGE(SH + ((i + 1) & 1) * 8192, (i + 1) * 32);
    s8v a[4], bb[4];
#pragma unroll
    for (int m = 0; m < 4; ++m) {
      const int R = wr * 64 + m * 16 + l;
      a[m] = *(const s8v*)(buf + R * 32 + ((g ^ lx3) * 8));
    }
#pragma unroll
    for (int n = 0; n < 4; ++n) {
      const int R = wc * 64 + n * 16 + l;
      bb[n] = *(const s8v*)(buf + 4096 + R * 32 + ((g ^ lx3) * 8));
    }
#pragma unroll
    for (int m = 0; m < 4; ++m)
#pragma unroll
      for (int n = 0; n < 4; ++n)
        acc[m][n] = MFMA16(a[m], bb[n], acc[m][n]);
    asm volatile("s_waitcnt lgkmcnt(0)" ::: "memory");
    asm volatile("s_waitcnt vmcnt(0)" ::: "memory");
    __builtin_amdgcn_sched_barrier(0);
    __builtin_amdgcn_s_barrier();
  }
#undef PSTAGE

  // ---- epilogue: bias + bf16 pack into LDS tile T[t 128][d 136], then
  // coalesced 16B global stores. (Final barrier above makes SH reuse safe.)
  u16* T = SH;
#pragma unroll
  for (int m = 0; m < 4; ++m)
#pragma unroll
    for (int n = 0; n < 4; ++n) {
      int d = wc * 64 + n * 16 + l;
      float bv = bias[tc + d];
      unsigned c01 = cvt_pk(acc[m][n][0] + bv, acc[m][n][1] + bv);
      unsigned c23 = cvt_pk(acc[m][n][2] + bv, acc[m][n][3] + bv);
      int t0 = wr * 64 + m * 16 + g * 4;
      T[(t0 + 0) * 136 + d] = (u16)c01;
      T[(t0 + 1) * 136 + d] = (u16)(c01 >> 16);
      T[(t0 + 2) * 136 + d] = (u16)c23;
      T[(t0 + 3) * 136 + d] = (u16)(c23 >> 16);
    }
  __syncthreads();
#pragma unroll
  for (int it = 0; it < 8; ++it) {
    int t = it * 16 + (tid >> 4);
    int c8 = (tid & 15) * 8;
    *(s8v*)(C + (size_t)(tr + t) * 1024 + tc + c8) = *(const s8v*)&T[t * 136 + c8];
  }
}

// ---------------- per-head V transpose: vT[hb][d][t] = vp[hb][t][d] ----------
__global__ void vtrans(const u16* __restrict__ vp, u16* __restrict__ vT) {
  const int hb = blockIdx.y;
  const int t0 = blockIdx.x * 64;
  const int tid = threadIdx.x;
  __shared__ u16 tl[64][65];
  const u16* vph = vp + (size_t)hb * HB_ELEMS;
  u16* vth = vT + (size_t)hb * HB_ELEMS;
#pragma unroll
  for (int it = 0; it < 4; ++it) {
    int i = (tid + it * 256) * 4;
    int r = i >> 6, c = i & 63;
    *(ushort4*)&tl[r][c] = *(const ushort4*)(vph + (size_t)(t0 + r) * 64 + c);
  }
  __syncthreads();
#pragma unroll
  for (int it = 0; it < 4; ++it) {
    int i = (tid + it * 256) * 4;
    int d = i >> 6, j = i & 63;
    ushort4 o;
    o.x = tl[j + 0][d]; o.y = tl[j + 1][d]; o.z = tl[j + 2][d]; o.w = tl[j + 3][d];
    *(ushort4*)(vth + (size_t)d * TSEQ + t0 + j) = o;
  }
}

// ---------------- fused attention: counted-vmcnt pipeline (both passes) -----
// grid: 512 blocks (16 qtiles x 32 heads, XCD-swizzled); 8 waves x 16 q-rows.
// (R22-proven; unchanged.)
__launch_bounds__(512, 2)
__global__ void attn_fused(const u16* __restrict__ qp, const u16* __restrict__ kp,
                           const u16* __restrict__ vT, float* __restrict__ attn,
                           float* __restrict__ ctx) {
  // XCD-bijective swizzle: all 16 q-tiles of a head share (hw & 7) -> same XCD
  const int hw = blockIdx.x + (blockIdx.y << 4);
  const int hb = (hw & 7) + ((hw >> 7) << 3);
  const int qt = (hw >> 3) & 15;

  const int tid = threadIdx.x;                    // 0..511
  const int w = tid >> 6, lane = tid & 63, g = lane >> 4, l = lane & 15;
  const int lx = l & 7;

  const u16* qh = qp + (size_t)hb * HB_ELEMS;
  const u16* kh = kp + (size_t)hb * HB_ELEMS;
  const u16* vh = vT + (size_t)hb * HB_ELEMS;

  // pass1: Ka/Kb dbuf 2x32KB. pass2: K0[2] 16KB | V0[2] 16KB | Pf 38KB = 70KB.
  __shared__ __align__(16) u16 SH[35840];

  const int row0 = qt * 128 + w * 16;             // wave's 16 q-rows
  const float scale = 0.125f;                     // dh^-0.5

  // staging geometry: thread t covers row (t>>3), 16B chunk t&7
  const int srow = tid >> 3;                      // 0..63
  const int swc = ((tid & 7) ^ (srow & 7)) * 8;   // swizzled source col (elems)

  // Q as B-operand fragment: lane (g,l) holds Q[row0+l][ks*32+g*8 .. +8)
  s8v qf0 = *(const s8v*)(qh + (size_t)(row0 + l) * 64 + g * 8);
  s8v qf1 = *(const s8v*)(qh + (size_t)(row0 + l) * 64 + 32 + g * 8);

  // ---- pass 1: row sums of exp(score); K double-buffered, 1 barrier/round --
#define STAGE1(buf, kt4_) do { const int c0_ = (kt4_) * 256;                    \
    _Pragma("unroll")                                                           \
    for (int c4 = 0; c4 < 4; ++c4)                                              \
      gl_lds16(kh + (size_t)(c0_ + c4 * 64 + srow) * 64 + swc,                  \
               (buf) + c4 * 4096 + tid * 8);                                    \
  } while (0)

  u16* Ka = SH;            // 32 KB
  u16* Kb = SH + 16384;    // 32 KB

  float sum = 0.0f;
  STAGE1(Ka, 0);
  asm volatile("s_waitcnt vmcnt(0)" ::: "memory");
  __builtin_amdgcn_sched_barrier(0);
  __builtin_amdgcn_s_barrier();
  for (int kt4 = 0; kt4 < 8; ++kt4) {
    const u16* kbuf = (kt4 & 1) ? Kb : Ka;
    if (kt4 < 7) STAGE1((kt4 & 1) ? Ka : Kb, kt4 + 1);
#pragma unroll
    for (int q4 = 0; q4 < 4; ++q4) {
#pragma unroll
      for (int n = 0; n < 4; ++n) {
        const u16* kr = kbuf + q4 * 4096 + (n * 16 + l) * 64;
        s8v b0 = *(const s8v*)(kr + (g ^ lx) * 8);
        s8v b1 = *(const s8v*)(kr + ((4 + g) ^ lx) * 8);
        f4v s = {};
        s = MFMA16(b0, qf0, s);
        s = MFMA16(b1, qf1, s);
        sum += __expf(s[0] * scale) + __expf(s[1] * scale)
             + __expf(s[2] * scale) + __expf(s[3] * scale);
      }
    }
    // reads of kbuf retired + next stage landed before crossing
    asm volatile("s_waitcnt lgkmcnt(0)" ::: "memory");
    asm volatile("s_waitcnt vmcnt(0)" ::: "memory");
    __builtin_amdgcn_sched_barrier(0);
    __builtin_amdgcn_s_barrier();
  }
#undef STAGE1
  // reduce across the 4 g-groups holding the same q-row l
  sum += __shfl_xor(sum, 16);
  sum += __shfl_xor(sum, 32);
  const float inv = 1.0f / sum;

  // ---- pass 2 (R21-proven counted-vmcnt pipeline) ----
  u16* K0 = SH;                       // [2][64][64] bf16 swizzled (16 KB)
  u16* V0 = SH + 8192;                // [2][64][64] bf16 swizzled (16 KB)
  float* Pf = (float*)(SH + 16384);   // [128][76] f32 P tile (38 KB)

#define STAGE2(b, kt_) do { const int c0_ = (kt_) * 64;                          \
    gl_lds16(kh + (size_t)(c0_ + srow) * 64 + swc, K0 + (b) * 4096 + tid * 8);   \
    gl_lds16(vh + (size_t)srow * TSEQ + c0_ + swc, V0 + (b) * 4096 + tid * 8);   \
  } while (0)

  f4v cacc[4] = {};
  float* attn_h = attn + (size_t)hb * TSEQ * TSEQ;
  const int kt0 = (qt * 2 + ((hw >> 7) << 3)) & 31;  // column-window rotation
  const int prow = w * 16 + l;                    // this lane's P row
  const int sr4 = lane >> 4;                      // store row-within-4group
  const int sc = (lane & 15) * 4;                 // store float col

  STAGE2(0, kt0);
  asm volatile("s_waitcnt vmcnt(0)" ::: "memory");
  __builtin_amdgcn_sched_barrier(0);
  __builtin_amdgcn_s_barrier();

  for (int i = 0; i < 32; ++i) {
    const int cur = i & 1;
    const int col0 = ((i + kt0) & 31) * 64;
    const u16* Kl = K0 + cur * 4096;
    const u16* Vl = V0 + cur * 4096;
    // issue next stage first: overlaps entire compute phase
    if (i < 31) STAGE2(cur ^ 1, (i + 1 + kt0) & 31);
#pragma unroll
    for (int n = 0; n < 4; ++n) {
      const u16* kr = Kl + (n * 16 + l) * 64;
      s8v b0 = *(const s8v*)(kr + (g ^ lx) * 8);
      s8v b1 = *(const s8v*)(kr + ((4 + g) ^ lx) * 8);
      f4v s = {};
      s = MFMA16(b0, qf0, s);
      s = MFMA16(b1, qf1, s);
      f4v p;
#pragma unroll
      for (int r = 0; r < 4; ++r) p[r] = __expf(s[r] * scale) * inv;
      *(f4v*)&Pf[prow * 76 + n * 16 + g * 4] = p;
    }
    // wave-local fence: drain this wave's Pf ds_writes before cross-lane reads
    asm volatile("s_waitcnt lgkmcnt(0)" ::: "memory");
    __builtin_amdgcn_sched_barrier(0);
    // PV: read wave-private P rows, pack bf16 on the fly
#pragma unroll
    for (int ks = 0; ks < 2; ++ks) {
      const float* pr = &Pf[prow * 76 + ks * 32 + g * 8];
      f4v r0 = *(const f4v*)pr;
      f4v r1 = *(const f4v*)(pr + 4);
      union { unsigned u[4]; s8v s; } pc;
      pc.u[0] = cvt_pk(r0[0], r0[1]);
      pc.u[1] = cvt_pk(r0[2], r0[3]);
      pc.u[2] = cvt_pk(r1[0], r1[1]);
      pc.u[3] = cvt_pk(r1[2], r1[3]);
      s8v pa = pc.s;
#pragma unroll
      for (int n4 = 0; n4 < 4; ++n4) {
        const u16* vr = Vl + (n4 * 16 + l) * 64;
        s8v bvv = *(const s8v*)(vr + ((ks * 4 + g) ^ lx) * 8);
        cacc[n4] = MFMA16(pa, bvv, cacc[n4]);
      }
    }
    // wave-local store: wave w flushes its OWN 16 rows (fence above covers
    // the cross-lane Pf reads; rows are wave-private). 256B/row coalesced.
#pragma unroll
    for (int r4 = 0; r4 < 4; ++r4) {
      const int row = w * 16 + r4 * 4 + sr4;
      f4v pv_ = *(const f4v*)&Pf[row * 76 + sc];
      *(f4v*)(attn_h + (size_t)(qt * 128 + row) * TSEQ + col0 + sc) = pv_;
    }
    if (i < 31) {
      // drain own ds reads (Kl/Vl/Pf) so other waves may overwrite post-
      // barrier; vmcnt(4): retires the 2 stage loads (issue order: stage
      // then 4 stores -> 4 newest outstanding are this iter's stores,
      // which REMAIN IN FLIGHT across the barrier).
      asm volatile("s_waitcnt lgkmcnt(0)" ::: "memory");
      asm volatile("s_waitcnt vmcnt(4)" ::: "memory");
      __builtin_amdgcn_sched_barrier(0);
      __builtin_amdgcn_s_barrier();
    }
  }
#undef STAGE2
  // write ctx (flat layout == (B,T,D) row-major); C row = q-row = g*4+r
#pragma unroll
  for (int n4 = 0; n4 < 4; ++n4)
#pragma unroll
    for (int r = 0; r < 4; ++r)
      ctx[(size_t)hb * HB_ELEMS + (size_t)(row0 + g * 4 + r) * 64 + n4 * 16 + l] =
          cacc[n4][r];
}

// ---------------- residual + LayerNorm ----------------
__global__ void ln_kernel(const float* __restrict__ q, const float* __restrict__ ctx,
                          const float* __restrict__ gam, const float* __restrict__ bet,
                          float* __restrict__ out) {
  const int row = blockIdx.x;
  const int tid = threadIdx.x;
  const float* qr = q + (size_t)row * 1024;
  const float* cr = ctx + (size_t)row * 1024;
  float4 xq = *(const float4*)(qr + tid * 4);
  float4 xc = *(const float4*)(cr + tid * 4);
  float x0 = xq.x + xc.x, x1 = xq.y + xc.y, x2 = xq.z + xc.z, x3 = xq.w + xc.w;
  float s1 = x0 + x1 + x2 + x3;
  float s2 = x0 * x0 + x1 * x1 + x2 * x2 + x3 * x3;
#pragma unroll
  for (int off = 1; off < 64; off <<= 1) {
    s1 += __shfl_xor(s1, off);
    s2 += __shfl_xor(s2, off);
  }
  __shared__ float ra[4], rb[4];
  int w = tid >> 6, lane = tid & 63;
  if (lane == 0) { ra[w] = s1; rb[w] = s2; }
  __syncthreads();
  s1 = ra[0] + ra[1] + ra[2] + ra[3];
  s2 = rb[0] + rb[1] + rb[2] + rb[3];
  float mu = s1 * (1.0f / 1024.0f);
  float var = s2 * (1.0f / 1024.0f) - mu * mu;
  float rstd = rsqrtf(var + 1e-5f);
  float4 gv = *(const float4*)(gam + tid * 4);
  float4 bv = *(const float4*)(bet + tid * 4);
  float4 o;
  o.x = (x0 - mu) * rstd * gv.x + bv.x;
  o.y = (x1 - mu) * rstd * gv.y + bv.y;
  o.z = (x2 - mu) * rstd * gv.z + bv.z;
  o.w = (x3 - mu) * rstd * gv.w + bv.w;
  *(float4*)(out + (size_t)row * 1024 + tid * 4) = o;
}

extern "C" void kernel_launch(void* const* d_in, const int* in_sizes, int n_in,
                              void* d_out, int out_size, void* d_ws, size_t ws_size,
                              hipStream_t stream) {
  const float* q    = (const float*)d_in[0];
  const float* k    = (const float*)d_in[1];
  const float* v    = (const float*)d_in[2];
  const float* wq   = (const float*)d_in[3];
  const float* bq   = (const float*)d_in[4];
  const float* wk   = (const float*)d_in[5];
  const float* bk   = (const float*)d_in[6];
  const float* wv   = (const float*)d_in[7];
  const float* bv   = (const float*)d_in[8];
  const float* ln_g = (const float*)d_in[9];
  const float* ln_b = (const float*)d_in[10];

  char* ws = (char*)d_ws;
  u16* qbf  = (u16*)(ws);              // 3 x 8 MiB   bf16 inputs (q,k,v)
  u16* wbf  = (u16*)(ws + 25165824);   // 3 x 2 MiB   bf16 weights (contig w/ qbf)
  u16* qp   = (u16*)(ws + 31457280);   // 3 x 8 MiB   bf16 projections (qp,kp,vp)
  u16* vT   = (u16*)(ws + 56623104);   // 8 MiB       per-head transposed V
  float* ctx = (float*)(ws + 65011712); // 16 MiB     fp32 context

  float* out  = (float*)d_out;
  float* attn = out + 4194304;

  cvt_all<<<15360, 256, 0, stream>>>(q, k, v, wq, wk, wv, qbf);

  proj_gemm<<<dim3(8, 32, 3), 256, 0, stream>>>(qbf, wbf, bq, bk, bv, qp);

  vtrans<<<dim3(32, 32), 256, 0, stream>>>(qp + 8388608, vT);

  attn_fused<<<dim3(16, 32), 512, 0, stream>>>(qp, qp + 4194304, vT, attn, ctx);

  ln_kernel<<<4096, 256, 0, stream>>>(q, ctx, ln_g, ln_b, out);
}